// Round 9
// baseline (372.368 us; speedup 1.0000x reference)
//
#include <hip/hip_runtime.h>
#include <hip/hip_bf16.h>
#include <math.h>

typedef __hip_bfloat16 bf16;

#define D_MODEL 512
#define NUM_HEADS 8
#define HEAD_DIM 64
#define SEQ_LEN 4096
#define BATCH 2
#define D_FF 2048
#define TOKENS (BATCH * SEQ_LEN)
#define QKV_STRIDE 1536
#define KSPLIT 2

typedef short short4v __attribute__((ext_vector_type(4)));
typedef short short8v __attribute__((ext_vector_type(8)));
typedef float float4v __attribute__((ext_vector_type(4)));

union frag_u { short8v v8; short4v v4[2]; short s[8]; };
union pack_u { unsigned u[2]; short4v v4; };

__device__ __forceinline__ float b2f(bf16 v) { return __bfloat162float(v); }
__device__ __forceinline__ bf16 f2b(float v) { return __float2bfloat16(v); }
__device__ __forceinline__ short f2bs(float v) { bf16 t = __float2bfloat16(v); return *(short*)&t; }
__device__ __forceinline__ float exp2fast(float x) { return __builtin_amdgcn_exp2f(x); }

// pack two f32 -> (bf16(hi)<<16)|bf16(lo), round-to-nearest via +0x8000 + v_perm
__device__ __forceinline__ unsigned pack_bf16(float lo, float hi) {
    unsigned a = __float_as_uint(hi) + 0x8000u;
    unsigned b = __float_as_uint(lo) + 0x8000u;
    return __builtin_amdgcn_perm(a, b, 0x07060302u);
}

#define AS1(p) ((__attribute__((address_space(1))) void*)(p))
#define AS3(p) ((__attribute__((address_space(3))) void*)(p))

// Self-detection: 1 if fp32 inputs, 0 if bf16.
__device__ __forceinline__ int self_detect(const unsigned* __restrict__ xw, int tid) {
    unsigned w = xw[tid & 63];
    unsigned e = (w >> 7) & 0xFFu;
    unsigned long long b = __ballot(e >= 110 && e <= 140);
    return __popcll(b) < 32;
}

// ---------------- fused weight prep (transposes + small vectors + flag) -------
__device__ __forceinline__ void do_tr(const void* __restrict__ src, bf16* __restrict__ dst,
                                      int K, int N, int n0, int k0, int fl, int tid,
                                      bf16 (*tile)[65]) {
    int c = tid & 63, r4 = tid >> 6;
#pragma unroll
    for (int t = 0; t < 16; t++) {
        int r = t * 4 + r4;
        size_t si = (size_t)(k0 + r) * N + n0 + c;
        float v = fl ? ((const float*)src)[si] : b2f(((const bf16*)src)[si]);
        tile[r][c] = f2b(v);
    }
    __syncthreads();
#pragma unroll
    for (int t = 0; t < 16; t++) {
        int r = t * 4 + r4;
        dst[(size_t)(n0 + r) * K + k0 + c] = tile[c][r];
    }
}

__global__ void prep_kernel(const void* x, const void* Wq, const void* Wk, const void* Wv,
                            const void* Wo, const void* W1, const void* W2,
                            const void* bq, const void* bk, const void* bv, const void* bo,
                            const void* b1, const void* b2,
                            const void* g1, const void* e1, const void* g2, const void* e2,
                            bf16* __restrict__ Wqkvt /* + Wot contiguous */,
                            bf16* __restrict__ W1t, bf16* __restrict__ W2t,
                            bf16* __restrict__ small, int* __restrict__ flag) {
    __shared__ bf16 tile[64][65];
    int blk = blockIdx.x, tid = threadIdx.x;
    int fl = self_detect((const unsigned*)x, tid);
    if (blk == 0 && tid == 0) flag[0] = fl;
    if (blk < 256) {                       // Wq|Wk|Wv|Wo 512x512
        int z = blk >> 6, tt = blk & 63;
        const void* src = (z == 0) ? Wq : (z == 1) ? Wk : (z == 2) ? Wv : Wo;
        do_tr(src, Wqkvt + (size_t)z * 512 * 512, 512, 512, (tt & 7) * 64, (tt >> 3) * 64,
              fl, tid, tile);
    } else if (blk < 512) {                // W1: [512][2048] -> [2048][512]
        int tt = blk - 256;
        do_tr(W1, W1t, 512, 2048, (tt & 31) * 64, (tt >> 5) * 64, fl, tid, tile);
    } else if (blk < 768) {                // W2: [2048][512] -> [512][2048]
        int tt = blk - 512;
        do_tr(W2, W2t, 2048, 512, (tt & 7) * 64, (tt >> 3) * 64, fl, tid, tile);
    } else {                               // small vectors
        int i = (blk - 768) * 256 + tid;   // 0..6655
        const void* src; int off;
        if (i < 512)       { src = bq; off = 0; }
        else if (i < 1024) { src = bk; off = 512; }
        else if (i < 1536) { src = bv; off = 1024; }
        else if (i < 2048) { src = bo; off = 1536; }
        else if (i < 4096) { src = b1; off = 2048; }
        else if (i < 4608) { src = b2; off = 4096; }
        else if (i < 5120) { src = g1; off = 4608; }
        else if (i < 5632) { src = e1; off = 5120; }
        else if (i < 6144) { src = g2; off = 5632; }
        else               { src = e2; off = 6144; }
        int j = i - off;
        small[i] = fl ? f2b(((const float*)src)[j]) : ((const bf16*)src)[j];
    }
}

// ---------------- LayerNorm: one block per token ------------------------------
// MODE: 0 = bf16 input, 2 = flag-chosen raw input.
template <int MODE>
__global__ void ln_kernel(const void* __restrict__ xv, const bf16* __restrict__ g,
                          const bf16* __restrict__ b, bf16* __restrict__ out,
                          const int* __restrict__ flag) {
    int t = blockIdx.x;
    int tid = threadIdx.x;
    int fl = (MODE == 2) ? *flag : 0;
    float v0, v1;
    if (fl) {
        const float* xr = (const float*)xv + (size_t)t * D_MODEL;
        v0 = xr[tid]; v1 = xr[tid + 256];
    } else {
        const bf16* xr = (const bf16*)xv + (size_t)t * D_MODEL;
        v0 = b2f(xr[tid]); v1 = b2f(xr[tid + 256]);
    }
    float s = v0 + v1, ss = v0 * v0 + v1 * v1;
    for (int o = 32; o > 0; o >>= 1) {
        s += __shfl_down(s, o);
        ss += __shfl_down(ss, o);
    }
    __shared__ float rs[4], rss[4], stat[2];
    int w = tid >> 6, l = tid & 63;
    if (l == 0) { rs[w] = s; rss[w] = ss; }
    __syncthreads();
    if (tid == 0) {
        float S = rs[0] + rs[1] + rs[2] + rs[3];
        float SS = rss[0] + rss[1] + rss[2] + rss[3];
        float mu = S / (float)D_MODEL;
        float var = SS / (float)D_MODEL - mu * mu;
        stat[0] = mu;
        stat[1] = rsqrtf(var + 1e-5f);
    }
    __syncthreads();
    float mu = stat[0], rstd = stat[1];
    bf16* orow = out + (size_t)t * D_MODEL;
    orow[tid]       = f2b((v0 - mu) * rstd * b2f(g[tid])       + b2f(b[tid]));
    orow[tid + 256] = f2b((v1 - mu) * rstd * b2f(g[tid + 256]) + b2f(b[tid + 256]));
}

__device__ __forceinline__ float gelu_tanh(float v) {
    float u = 0.7978845608f * (v + 0.044715f * v * v * v);
    float e2 = __expf(-2.f * u);
    return v / (1.f + e2);
}

// ---------------- MFMA GEMM 128x128 (m97 structure) ---------------------------
template <int ACT>
__global__ __launch_bounds__(256) void mfma_gemm(
    const bf16* __restrict__ A, const bf16* __restrict__ Wt,
    const bf16* __restrict__ bias, bf16* __restrict__ Cout,
    int M, int N, int K) {
    __shared__ bf16 As[128 * 64];
    __shared__ bf16 Bs[128 * 64];
    int tid = threadIdx.x, wave = tid >> 6, lane = tid & 63;
    int m = lane & 15, g = lane >> 4;
    int row0 = blockIdx.y * 128, col0 = blockIdx.x * 128;
    int R0 = (wave >> 1) * 64, C0 = (wave & 1) * 64;
    float4v acc[4][4] = {};

    int srow = lane >> 3;
    int scol = (lane & 7) * 8;
    const bf16* Ab = A  + (size_t)(row0 + wave * 8 + srow) * K + scol;
    const bf16* Bb = Wt + (size_t)(col0 + wave * 8 + srow) * K + scol;

    for (int k0 = 0; k0 < K; k0 += 64) {
#pragma unroll
        for (int t = 0; t < 4; t++) {
            int rbase = t * 32 + wave * 8;
            __builtin_amdgcn_global_load_lds(AS1(Ab + (size_t)(t * 32) * K + k0),
                                             AS3(&As[rbase * 64]), 16, 0, 0);
            __builtin_amdgcn_global_load_lds(AS1(Bb + (size_t)(t * 32) * K + k0),
                                             AS3(&Bs[rbase * 64]), 16, 0, 0);
        }
        __syncthreads();
#pragma unroll
        for (int kk = 0; kk < 2; kk++) {
            short8v fa[4], fb[4];
#pragma unroll
            for (int i = 0; i < 4; i++)
                fa[i] = *(const short8v*)&As[(R0 + i * 16 + m) * 64 + kk * 32 + g * 8];
#pragma unroll
            for (int j = 0; j < 4; j++)
                fb[j] = *(const short8v*)&Bs[(C0 + j * 16 + m) * 64 + kk * 32 + g * 8];
#pragma unroll
            for (int i = 0; i < 4; i++)
#pragma unroll
                for (int j = 0; j < 4; j++)
                    acc[i][j] = __builtin_amdgcn_mfma_f32_16x16x32_bf16(fa[i], fb[j], acc[i][j], 0, 0, 0);
        }
        __syncthreads();
    }

#pragma unroll
    for (int i = 0; i < 4; i++) {
#pragma unroll
        for (int r = 0; r < 4; r++) {
            int row = row0 + R0 + i * 16 + g * 4 + r;
#pragma unroll
            for (int j = 0; j < 4; j++) {
                int col = col0 + C0 + j * 16 + m;
                float v = acc[i][j][r] + b2f(bias[col]);
                if (ACT == 1) v = gelu_tanh(v);
                Cout[(size_t)row * N + col] = f2b(v);
            }
        }
    }
}

// ---------------- MFMA GEMM 128x64 tile (N=512 GEMMs: 512 blocks) -------------
// RES: 2 bf16 res, 3 raw-input res (dtype per flag). OUTMODE: 0 bf16, 2 flag.
template <int RES, int OUTMODE>
__global__ __launch_bounds__(256) void mfma_gemm64(
    const bf16* __restrict__ A, const bf16* __restrict__ Wt,
    const bf16* __restrict__ bias, const void* __restrict__ res,
    void* __restrict__ Cout, const int* __restrict__ flag, int M, int N, int K) {
    __shared__ bf16 As[128 * 64];
    __shared__ bf16 Bs[64 * 64];
    int tid = threadIdx.x, wave = tid >> 6, lane = tid & 63;
    int m = lane & 15, g = lane >> 4;
    int row0 = blockIdx.y * 128, col0 = blockIdx.x * 64;
    int R0 = wave * 32;
    int fl = (OUTMODE == 2 || RES == 3) ? *flag : 0;
    float4v acc[2][4] = {};

    int srow = lane >> 3;
    int scol = (lane & 7) * 8;
    const bf16* Ab = A  + (size_t)(row0 + wave * 8 + srow) * K + scol;
    const bf16* Bb = Wt + (size_t)(col0 + wave * 8 + srow) * K + scol;

    for (int k0 = 0; k0 < K; k0 += 64) {
#pragma unroll
        for (int t = 0; t < 4; t++) {
            __builtin_amdgcn_global_load_lds(AS1(Ab + (size_t)(t * 32) * K + k0),
                                             AS3(&As[(t * 32 + wave * 8) * 64]), 16, 0, 0);
            if (t < 2)
                __builtin_amdgcn_global_load_lds(AS1(Bb + (size_t)(t * 32) * K + k0),
                                                 AS3(&Bs[(t * 32 + wave * 8) * 64]), 16, 0, 0);
        }
        __syncthreads();
#pragma unroll
        for (int kk = 0; kk < 2; kk++) {
            short8v fa[2], fb[4];
#pragma unroll
            for (int i = 0; i < 2; i++)
                fa[i] = *(const short8v*)&As[(R0 + i * 16 + m) * 64 + kk * 32 + g * 8];
#pragma unroll
            for (int j = 0; j < 4; j++)
                fb[j] = *(const short8v*)&Bs[(j * 16 + m) * 64 + kk * 32 + g * 8];
#pragma unroll
            for (int i = 0; i < 2; i++)
#pragma unroll
                for (int j = 0; j < 4; j++)
                    acc[i][j] = __builtin_amdgcn_mfma_f32_16x16x32_bf16(fa[i], fb[j], acc[i][j], 0, 0, 0);
        }
        __syncthreads();
    }

#pragma unroll
    for (int i = 0; i < 2; i++) {
#pragma unroll
        for (int r = 0; r < 4; r++) {
            int row = row0 + R0 + i * 16 + g * 4 + r;
#pragma unroll
            for (int j = 0; j < 4; j++) {
                int col = col0 + j * 16 + m;
                float v = acc[i][j][r] + b2f(bias[col]);
                size_t idx = (size_t)row * N + col;
                if (RES == 2) v += b2f(((const bf16*)res)[idx]);
                if (RES == 3) v += fl ? ((const float*)res)[idx]
                                      : b2f(((const bf16*)res)[idx]);
                if (OUTMODE == 0) ((bf16*)Cout)[idx] = f2b(v);
                else {
                    if (fl) ((float*)Cout)[idx] = v;
                    else ((bf16*)Cout)[idx] = f2b(v);
                }
            }
        }
    }
}

// ---------------- V transpose: qkvb V-part -> Vt_g [bh][dim][seq] -------------
__global__ void v_transpose(const bf16* __restrict__ qkv, bf16* __restrict__ Vt_g) {
    __shared__ bf16 tile[64][65];
    int s0 = blockIdx.x * 64;
    int bh = blockIdx.y;
    int b = bh >> 3, h = bh & 7;
    int c = threadIdx.x & 63, r4 = threadIdx.x >> 6;
    const bf16* src = qkv + ((size_t)b * SEQ_LEN + s0) * QKV_STRIDE + 1024 + h * 64;
#pragma unroll
    for (int t = 0; t < 16; t++) {
        int r = t * 4 + r4;
        tile[r][c] = src[(size_t)r * QKV_STRIDE + c];
    }
    __syncthreads();
    bf16* dst = Vt_g + (size_t)bh * 64 * SEQ_LEN + s0;
#pragma unroll
    for (int t = 0; t < 16; t++) {
        int r = t * 4 + r4;
        dst[(size_t)r * SEQ_LEN + c] = tile[c][r];
    }
}

// ---------------- Flash attention: 256q/block, 64q/wave (4 m-tiles) -----------
// S^T formulation; K/V A-operand LDS reads amortized over 4 m-tiles.
// Global staging loads prefetched one tile ahead into registers.
__global__ __launch_bounds__(256, 2) void flash_attn(const bf16* __restrict__ Q,
                                                     const bf16* __restrict__ K,
                                                     const bf16* __restrict__ Vt_g,
                                                     bf16* __restrict__ Op,
                                                     float2* __restrict__ mlout) {
    __shared__ bf16 Ks[64][72];
    __shared__ bf16 Vt[64][72];
    __shared__ bf16 Pt[4][64][72];   // per-wave P^T [q_local][k]

    int tid = threadIdx.x;
    int wave = tid >> 6, lane = tid & 63;
    int m = lane & 15, g = lane >> 4;

    int bh = blockIdx.y;
    size_t base = (size_t)(bh >> 3) * SEQ_LEN * QKV_STRIDE + (size_t)(bh & 7) * HEAD_DIM;
    int q0w = blockIdx.x * 256 + wave * 64;

    const float qscale = 0.125f * 1.44269504f;   // fold log2(e) -> exp2 softmax
    short8v aQ[4][2];
#pragma unroll
    for (int mt = 0; mt < 4; mt++) {
        const bf16* qp = Q + base + (size_t)(q0w + mt * 16 + m) * QKV_STRIDE + g * 8;
#pragma unroll
        for (int c = 0; c < 2; c++) {
            frag_u u;
#pragma unroll
            for (int j = 0; j < 8; j++) u.s[j] = f2bs(b2f(qp[c * 32 + j]) * qscale);
            aQ[mt][c] = u.v8;
        }
    }

    float mrow[4] = {-1e30f, -1e30f, -1e30f, -1e30f};
    float lrow[4] = {0.f, 0.f, 0.f, 0.f};
    float4v oacc[4][4] = {};   // [mt][dt]

    int sk = tid >> 2, sd = (tid & 3) * 16;
    int vrow = tid >> 2, vcol = (tid & 3) * 16;

    const unsigned short* Ku = (const unsigned short*)(K + base);
    const unsigned short* Vg = (const unsigned short*)Vt_g +
                               (size_t)bh * 64 * SEQ_LEN + (size_t)vrow * SEQ_LEN;

    int t0 = blockIdx.z * (64 / KSPLIT);
    int t1 = t0 + 64 / KSPLIT;

    // prefetch tile t0
    short8v gK0, gK1, gV0, gV1;
    {
        const unsigned short* kp = Ku + (size_t)(t0 * 64 + sk) * QKV_STRIDE + sd;
        gK0 = *(const short8v*)(kp);
        gK1 = *(const short8v*)(kp + 8);
        gV0 = *(const short8v*)(Vg + t0 * 64 + vcol);
        gV1 = *(const short8v*)(Vg + t0 * 64 + vcol + 8);
    }

    for (int t = t0; t < t1; t++) {
        __syncthreads();   // previous tile's LDS reads done
        *(short8v*)&Ks[sk][sd]       = gK0;
        *(short8v*)&Ks[sk][sd + 8]   = gK1;
        *(short8v*)&Vt[vrow][vcol]     = gV0;
        *(short8v*)&Vt[vrow][vcol + 8] = gV1;
        __syncthreads();

        // prefetch next tile's globals (latency hidden by compute below)
        int tn = (t + 1 < t1) ? t + 1 : t;
        {
            const unsigned short* kp = Ku + (size_t)(tn * 64 + sk) * QKV_STRIDE + sd;
            gK0 = *(const short8v*)(kp);
            gK1 = *(const short8v*)(kp + 8);
            gV0 = *(const short8v*)(Vg + tn * 64 + vcol);
            gV1 = *(const short8v*)(Vg + tn * 64 + vcol + 8);
        }

        // St: K frags loaded once per kt, shared across 4 m-tiles
        float4v st[4][4];   // [mt][kt]
#pragma unroll
        for (int kt = 0; kt < 4; kt++) {
            short8v bK0 = *(const short8v*)&Ks[kt * 16 + m][g * 8];
            short8v bK1 = *(const short8v*)&Ks[kt * 16 + m][32 + g * 8];
#pragma unroll
            for (int mt = 0; mt < 4; mt++) {
                float4v a = {0.f, 0.f, 0.f, 0.f};
                a = __builtin_amdgcn_mfma_f32_16x16x32_bf16(bK0, aQ[mt][0], a, 0, 0, 0);
                a = __builtin_amdgcn_mfma_f32_16x16x32_bf16(bK1, aQ[mt][1], a, 0, 0, 0);
                st[mt][kt] = a;
            }
        }

        // online softmax per m-tile (exp2 domain)
#pragma unroll
        for (int mt = 0; mt < 4; mt++) {
            float tm = st[mt][0][0];
#pragma unroll
            for (int kt = 0; kt < 4; kt++)
#pragma unroll
                for (int r = 0; r < 4; r++) tm = fmaxf(tm, st[mt][kt][r]);
            tm = fmaxf(tm, __shfl_xor(tm, 16));
            tm = fmaxf(tm, __shfl_xor(tm, 32));
            float mnew = fmaxf(mrow[mt], tm);
            float alpha = exp2fast(mrow[mt] - mnew);
            mrow[mt] = mnew;

            float psum = 0.f;
#pragma unroll
            for (int kt = 0; kt < 4; kt++) {
                float p0 = exp2fast(st[mt][kt][0] - mnew);
                float p1 = exp2fast(st[mt][kt][1] - mnew);
                float p2 = exp2fast(st[mt][kt][2] - mnew);
                float p3 = exp2fast(st[mt][kt][3] - mnew);
                psum += (p0 + p1) + (p2 + p3);
                pack_u pp;
                pp.u[0] = pack_bf16(p0, p1);
                pp.u[1] = pack_bf16(p2, p3);
                *(short4v*)&Pt[wave][mt * 16 + m][kt * 16 + g * 4] = pp.v4;
            }
            lrow[mt] = lrow[mt] * alpha + psum;
#pragma unroll
            for (int dt = 0; dt < 4; dt++)
#pragma unroll
                for (int r = 0; r < 4; r++) oacc[mt][dt][r] *= alpha;
        }

        // P^T B-frags per m-tile (b128 reads)
        short8v bP[4][2];
#pragma unroll
        for (int mt = 0; mt < 4; mt++)
#pragma unroll
            for (int c = 0; c < 2; c++)
                bP[mt][c] = *(const short8v*)&Pt[wave][mt * 16 + m][c * 32 + g * 8];

        // PV: Vt A-frags loaded once (b128), used for all 4 m-tiles
#pragma unroll
        for (int dt = 0; dt < 4; dt++) {
#pragma unroll
            for (int c = 0; c < 2; c++) {
                short8v vfrag = *(const short8v*)&Vt[dt * 16 + m][c * 32 + g * 8];
#pragma unroll
                for (int mt = 0; mt < 4; mt++)
                    oacc[mt][dt] = __builtin_amdgcn_mfma_f32_16x16x32_bf16(vfrag, bP[mt][c], oacc[mt][dt], 0, 0, 0);
            }
        }
    }

    size_t zoff = (size_t)blockIdx.z * NUM_HEADS * BATCH + bh;
    size_t pbase = zoff * (SEQ_LEN * (size_t)HEAD_DIM);
#pragma unroll
    for (int mt = 0; mt < 4; mt++) {
        float l = lrow[mt];
        l += __shfl_xor(l, 16);
        l += __shfl_xor(l, 32);
        int q = q0w + mt * 16 + m;
        bf16* orow = Op + pbase + (size_t)q * HEAD_DIM;
#pragma unroll
        for (int dt = 0; dt < 4; dt++) {
            pack_u oo;
            oo.u[0] = pack_bf16(oacc[mt][dt][0], oacc[mt][dt][1]);
            oo.u[1] = pack_bf16(oacc[mt][dt][2], oacc[mt][dt][3]);
            *(short4v*)&orow[dt * 16 + g * 4] = oo.v4;
        }
        if (g == 0) mlout[zoff * SEQ_LEN + q] = make_float2(mrow[mt], l);
    }
}

// Merge KSPLIT=2 partials -> ab [TOKENS][D_MODEL]; 4 dims per thread (b64)
__global__ void attn_merge(const bf16* __restrict__ Op, const float2* __restrict__ ml,
                           bf16* __restrict__ O) {
    int i = blockIdx.x * 256 + threadIdx.x;   // over 16*4096*16
    int d4 = (i & 15) * 4;
    int q = (i >> 4) & (SEQ_LEN - 1);
    int bh = i >> 16;
    const int HQ = NUM_HEADS * BATCH * SEQ_LEN;
    float2 a0 = ml[bh * SEQ_LEN + q];
    float2 a1 = ml[HQ + bh * SEQ_LEN + q];
    float M = fmaxf(a0.x, a1.x);
    float w0 = exp2fast(a0.x - M), w1 = exp2fast(a1.x - M);
    float inv = 1.f / (a0.y * w0 + a1.y * w1);
    const size_t NP = (size_t)HQ * HEAD_DIM;
    size_t idx = ((size_t)bh * SEQ_LEN + q) * HEAD_DIM + d4;
    frag_u u0, u1;
    u0.v4[0] = *(const short4v*)&Op[idx];
    u1.v4[0] = *(const short4v*)&Op[NP + idx];
    float o[4];
#pragma unroll
    for (int j = 0; j < 4; j++) {
        bf16 b0 = *(bf16*)&u0.s[j];
        bf16 b1 = *(bf16*)&u1.s[j];
        o[j] = (b2f(b0) * w0 + b2f(b1) * w1) * inv;
    }
    pack_u oo;
    oo.u[0] = pack_bf16(o[0], o[1]);
    oo.u[1] = pack_bf16(o[2], o[3]);
    *(short4v*)&O[((size_t)((bh >> 3) * SEQ_LEN + q)) * D_MODEL + (bh & 7) * HEAD_DIM + d4] = oo.v4;
}

// ------------------------------------------------------------------------------
extern "C" void kernel_launch(void* const* d_in, const int* in_sizes, int n_in,
                              void* d_out, int out_size, void* d_ws, size_t ws_size,
                              hipStream_t stream) {
    const void* x     = d_in[0];
    const void* Wq    = d_in[1];
    const void* bq    = d_in[2];
    const void* Wk    = d_in[3];
    const void* bk    = d_in[4];
    const void* Wv    = d_in[5];
    const void* bv    = d_in[6];
    const void* Wo    = d_in[7];
    const void* bo    = d_in[8];
    const void* ln1_g = d_in[9];
    const void* ln1_b = d_in[10];
    const void* ln2_g = d_in[11];
    const void* ln2_b = d_in[12];
    const void* W1    = d_in[13];
    const void* b1    = d_in[14];
    const void* W2    = d_in[15];
    const void* b2    = d_in[16];

    // ---- workspace layout ----
    char* p = (char*)d_ws;
    int* flag = (int*)p;                      p += 256;
    size_t tok_d = (size_t)TOKENS * D_MODEL;
    // region2: KSPLIT bf16 O-partials (16.8 MB) overlay x1b+hb (16.8 MB)
    char* region2 = p;                        p += 2 * tok_d * 2;
    bf16* x1b   = (bf16*)region2;
    bf16* hb    = (bf16*)(region2 + tok_d * 2);
    bf16* Opart = (bf16*)region2;
    bf16*  bigA = (bf16*)p;                   p += (size_t)TOKENS * D_FF * 2;  // 33.6 MB
    bf16*  qkvb = bigA;                                   // [TOKENS][1536]
    bf16*  ab   = bigA + (size_t)TOKENS * QKV_STRIDE;     // [TOKENS][512]
    bf16*  ffb  = bigA;                                   // [TOKENS][2048]
    bf16*  Wqkvt = (bf16*)p;                  p += (size_t)QKV_STRIDE * D_MODEL * 2;
    bf16*  Wot   = (bf16*)p;                  p += (size_t)D_MODEL * D_MODEL * 2;  // contiguous
    bf16*  W1t   = (bf16*)p;                  p += (size_t)D_FF * D_MODEL * 2;
    bf16*  W2t   = (bf16*)p;                  p += (size_t)D_MODEL * D_FF * 2;
    bf16*  Vtg   = (bf16*)p;                  p += (size_t)NUM_HEADS * BATCH * HEAD_DIM * SEQ_LEN * 2;
    float2* mlb  = (float2*)p;                p += (size_t)KSPLIT * NUM_HEADS * BATCH * SEQ_LEN * sizeof(float2);
    bf16*  small = (bf16*)p;                  p += 6656 * 2;
    bf16* bias_qkv = small + 0;
    bf16* bias_o   = small + 1536;
    bf16* b1b      = small + 2048;
    bf16* b2b      = small + 4096;
    bf16* g1b      = small + 4608;
    bf16* be1b     = small + 5120;
    bf16* g2b      = small + 5632;
    bf16* be2b     = small + 6144;

    prep_kernel<<<794, 256, 0, stream>>>(x, Wq, Wk, Wv, Wo, W1, W2,
                                         bq, bk, bv, bo, b1, b2,
                                         ln1_g, ln1_b, ln2_g, ln2_b,
                                         Wqkvt, W1t, W2t, small, flag);

    ln_kernel<2><<<TOKENS, 256, 0, stream>>>(x, g1b, be1b, hb, flag);

    mfma_gemm<0><<<dim3(QKV_STRIDE / 128, TOKENS / 128), 256, 0, stream>>>(
        hb, Wqkvt, bias_qkv, qkvb, TOKENS, QKV_STRIDE, D_MODEL);

    v_transpose<<<dim3(SEQ_LEN / 64, NUM_HEADS * BATCH), 256, 0, stream>>>(qkvb, Vtg);

    flash_attn<<<dim3(SEQ_LEN / 256, 16, KSPLIT), 256, 0, stream>>>(
        qkvb, qkvb + 512, Vtg, Opart, mlb);
    attn_merge<<<(NUM_HEADS * BATCH * SEQ_LEN * HEAD_DIM) / (256 * 4), 256, 0, stream>>>(
        Opart, mlb, ab);

    mfma_gemm64<3, 0><<<dim3(D_MODEL / 64, TOKENS / 128), 256, 0, stream>>>(
        ab, Wot, bias_o, x, x1b, flag, TOKENS, D_MODEL, D_MODEL);

    ln_kernel<0><<<TOKENS, 256, 0, stream>>>(x1b, g2b, be2b, hb, flag);

    mfma_gemm<1><<<dim3(D_FF / 128, TOKENS / 128), 256, 0, stream>>>(
        hb, W1t, b1b, ffb, TOKENS, D_FF, D_MODEL);

    mfma_gemm64<2, 2><<<dim3(D_MODEL / 64, TOKENS / 128), 256, 0, stream>>>(
        ffb, W2t, b2b, x1b, d_out, flag, TOKENS, D_MODEL, D_FF);
}